// Round 19
// baseline (74.195 us; speedup 1.0000x reference)
//
#include <hip/hip_runtime.h>
#include <math.h>

#define NX 128
#define NY 128
#define NZ 64
#define NVOX (NX * NY * NZ)   // 1048576 = 1<<20
#define NC 32
#define FH 120
#define FW 160
#define FHW (FH * FW)         // 19200
#define VOXSZ 0.04f
#define NB 2

// Single kernel, one thread per voxel (R18 structure). No transpose stage:
// gather straight from feat (L2-resident, 4.9 MB); neighbor threads hit
// neighbor pixels -> good per-instruction line locality.
// Projection = PINNED R14 pipeline (f32, contract off, pairwise association,
// IEEE div, rndne) -- bit-exact vs harness reference.
// Stores: normal cached stores (R18-proven fast path).
__global__ __launch_bounds__(256) void voxel_backproject_kernel(
    const float* __restrict__ proj,
    const float* __restrict__ feat,
    const float* __restrict__ origin,
    float* __restrict__ out)
{
#pragma clang fp contract(off)
    const int tid = blockIdx.x * 256 + threadIdx.x;
    const int b = tid >> 20;
    const int n = tid & (NVOX - 1);
    const int i = n >> 13;
    const int j = (n >> 6) & (NY - 1);
    const int k = n & (NZ - 1);

    const float* P = proj + b * 12;
    const float ox = origin[b * 3 + 0];
    const float oy = origin[b * 3 + 1];
    const float oz = origin[b * 3 + 2];

    const float wx = (float)i * VOXSZ + ox;
    const float wy = (float)j * VOXSZ + oy;
    const float wz = (float)k * VOXSZ + oz;

    const float tx = P[0] * wx + P[1] * wy;
    const float ty = P[4] * wx + P[5] * wy;
    const float tz = P[8] * wx + P[9] * wy;

    const float cx = tx + (P[2]  * wz + P[3]);
    const float cy = ty + (P[6]  * wz + P[7]);
    const float cz = tz + (P[10] * wz + P[11]);

    const float qx = cx / cz;
    const float qy = cy / cz;
    const int px = __float2int_rn(qx);
    const int py = __float2int_rn(qy);
    const bool v = (px >= 0) & (py >= 0) & (px < FW) & (py < FH) & (cz > 0.0f);

    float r[NC];
    #pragma unroll
    for (int c = 0; c < NC; ++c) r[c] = 0.0f;
    if (v) {
        const int idx = py * FW + px;
        const float* fb = feat + (size_t)b * NC * FHW + idx;
        #pragma unroll
        for (int c = 0; c < NC; ++c) r[c] = fb[(size_t)c * FHW];
    }

    float* ob = out + (size_t)b * NC * NVOX + n;
    #pragma unroll
    for (int c = 0; c < NC; ++c)
        ob[(size_t)c * NVOX] = r[c];

    out[(size_t)NB * NC * NVOX + (size_t)b * NVOX + n] = v ? 1.0f : 0.0f;
}

extern "C" void kernel_launch(void* const* d_in, const int* in_sizes, int n_in,
                              void* d_out, int out_size, void* d_ws, size_t ws_size,
                              hipStream_t stream) {
    const float* proj   = (const float*)d_in[0];
    const float* feat   = (const float*)d_in[1];
    const float* origin = (const float*)d_in[2];
    float* out = (float*)d_out;

    const int total = NB * NVOX;                      // 2097152
    voxel_backproject_kernel<<<total / 256, 256, 0, stream>>>(proj, feat, origin, out);
}